// Round 1
// baseline (337.537 us; speedup 1.0000x reference)
//
#include <hip/hip_runtime.h>
#include <cstdint>

// FCOS post-processor, MI355X. Pipeline:
//  k_init      : zero histogram + counters in ws
//  k_hist      : sm = cand ? sigmoid(cls)*sigmoid(ctr) : NEG ; 4096-bin histogram per image
//  k_findbin   : suffix-scan histogram -> threshold bin b* (top-1000 boundary)
//  k_collect   : recompute sm, collect (val,idx) with bin >= b*  (~1005 per image)
//  k_sortdecode: bitonic sort 4096 slots (val desc, idx asc == jax top_k tie-break),
//                decode+clip top-1000 boxes, store boxes+scores
//  k_edges     : all pairs i<j with IoU>0.6 -> tiny edge list (conflicts are rare)
//  k_final     : sort edges, exact greedy NMS over edges, prefix-select first 100 kept,
//                write dets/labels/fvalid (labels+fvalid as 0.0/1.0 floats)

#define NIMG 16
#define HH 400
#define WW 608
#define HW 243200
#define TOPK 1000
#define NBINS 4096
#define CCAP 4096
#define ECAP 8192
#define NEGV (-1e9f)

__device__ __forceinline__ float sigm(float x) { return 1.0f / (1.0f + expf(-x)); }

__device__ __forceinline__ int binof(float v) {
  if (!(v > 0.0f)) return 0;
  int b = (int)(v * (float)NBINS);
  return b > (NBINS - 1) ? (NBINS - 1) : b;
}

__global__ void k_init(unsigned* hist, unsigned* bstar, unsigned* ccount, unsigned* ecnt) {
  int i = blockIdx.x * blockDim.x + threadIdx.x;
  int tot = NIMG * NBINS;
  for (int k = i; k < tot; k += gridDim.x * blockDim.x) hist[k] = 0u;
  if (i < NIMG) { bstar[i] = 0u; ccount[i] = 0u; ecnt[i] = 0u; }
}

#define HB_ELEMS 32
__global__ void k_hist(const float* __restrict__ cls, const float* __restrict__ ctr,
                       unsigned* __restrict__ hist) {
  __shared__ unsigned lh[NBINS];
  const int n = blockIdx.y;
  for (int b = threadIdx.x; b < NBINS; b += blockDim.x) lh[b] = 0u;
  __syncthreads();
  const float* c = cls + n * HW;
  const float* t = ctr + n * HW;
  int base = blockIdx.x * (blockDim.x * HB_ELEMS);
  for (int e = 0; e < HB_ELEMS; ++e) {
    int i = base + e * blockDim.x + threadIdx.x;
    if (i < HW) {
      float sc = sigm(c[i]);
      float s  = sc * sigm(t[i]);
      float sm = (sc > 0.05f) ? s : NEGV;
      atomicAdd(&lh[binof(sm)], 1u);
    }
  }
  __syncthreads();
  unsigned* gh = hist + n * NBINS;
  for (int b = threadIdx.x; b < NBINS; b += blockDim.x)
    if (lh[b]) atomicAdd(&gh[b], lh[b]);
}

__global__ void k_findbin(const unsigned* __restrict__ hist, unsigned* __restrict__ bstar) {
  __shared__ unsigned chunk[256];
  const int n = blockIdx.x;
  const unsigned* h = hist + n * NBINS;
  unsigned s = 0;
  int c = threadIdx.x;
  for (int k = 0; k < 16; ++k) s += h[c * 16 + k];
  chunk[c] = s;
  __syncthreads();
  if (threadIdx.x == 0) {
    unsigned cum = 0; int bs = 0; int cc;
    for (cc = 255; cc >= 0; --cc) {
      if (cum + chunk[cc] >= TOPK) break;
      cum += chunk[cc];
    }
    if (cc >= 0) {
      int b = cc * 16 + 15;
      for (;;) { cum += h[b]; if (cum >= TOPK || b == cc * 16) break; --b; }
      bs = b;
    }
    bstar[n] = (unsigned)bs;
  }
}

__global__ void k_collect(const float* __restrict__ cls, const float* __restrict__ ctr,
                          const unsigned* __restrict__ bstar,
                          unsigned* __restrict__ ccount,
                          float* __restrict__ cval, unsigned* __restrict__ cidx) {
  const int n = blockIdx.y;
  const unsigned bs = bstar[n];
  const float* c = cls + n * HW;
  const float* t = ctr + n * HW;
  int base = blockIdx.x * (blockDim.x * HB_ELEMS);
  for (int e = 0; e < HB_ELEMS; ++e) {
    int i = base + e * blockDim.x + threadIdx.x;
    if (i < HW) {
      float sc = sigm(c[i]);
      float s  = sc * sigm(t[i]);
      float sm = (sc > 0.05f) ? s : NEGV;
      if ((unsigned)binof(sm) >= bs) {
        unsigned p = atomicAdd(&ccount[n], 1u);
        if (p < CCAP) { cval[n * CCAP + p] = sm; cidx[n * CCAP + p] = (unsigned)i; }
      }
    }
  }
}

__global__ __launch_bounds__(1024) void k_sortdecode(
    const unsigned* __restrict__ ccount,
    const float* __restrict__ cval, const unsigned* __restrict__ cidx,
    const float* __restrict__ reg, const int* __restrict__ isz,
    float* __restrict__ boxes, float* __restrict__ bscores) {
  __shared__ float sv[CCAP];
  __shared__ int   si[CCAP];
  const int n = blockIdx.x;
  const int tid = threadIdx.x;
  unsigned M = ccount[n]; if (M > CCAP) M = CCAP;
  for (int e = tid; e < CCAP; e += 1024) {
    if (e < (int)M) { sv[e] = cval[n * CCAP + e]; si[e] = (int)cidx[n * CCAP + e]; }
    else            { sv[e] = NEGV; si[e] = 0x7fffffff; }
  }
  for (int k = 2; k <= CCAP; k <<= 1) {
    for (int j = k >> 1; j > 0; j >>= 1) {
      __syncthreads();
      for (int e = tid; e < CCAP; e += 1024) {
        int p = e ^ j;
        if (p > e) {
          float v0 = sv[e], v1 = sv[p];
          int   i0 = si[e], i1 = si[p];
          bool before_pe = (v1 > v0) || (v1 == v0 && i1 < i0); // p-elem should precede e-elem
          bool before_ep = (v0 > v1) || (v0 == v1 && i0 < i1);
          bool dir = ((e & k) == 0);
          if (dir ? before_pe : before_ep) {
            sv[e] = v1; sv[p] = v0; si[e] = i1; si[p] = i0;
          }
        }
      }
    }
  }
  __syncthreads();
  const float wmax = (float)(isz[n * 2 + 1] - 1);
  const float hmax = (float)(isz[n * 2 + 0] - 1);
  const float* rg = reg + (size_t)n * 4 * HW;
  for (int r = tid; r < TOPK; r += 1024) {
    float val = sv[r]; int gi = si[r];
    float x1 = 0.f, y1 = 0.f, x2 = 0.f, y2 = 0.f, scr = NEGV;
    if (val > NEGV * 0.5f) {
      int wx = gi % WW, hy = gi / WW;
      float lx = (float)(wx * 8 + 4), ly = (float)(hy * 8 + 4);
      float l  = rg[0 * HW + gi], tt = rg[1 * HW + gi];
      float rr = rg[2 * HW + gi], bb = rg[3 * HW + gi];
      x1 = lx - l;  y1 = ly - tt;  x2 = lx + rr;  y2 = ly + bb;
      x1 = fminf(fmaxf(x1, 0.0f), wmax);
      x2 = fminf(fmaxf(x2, 0.0f), wmax);
      y1 = fminf(fmaxf(y1, 0.0f), hmax);
      y2 = fminf(fmaxf(y2, 0.0f), hmax);
      scr = val;
      if (!(((x2 - x1 + 1.0f) >= 0.0f) && ((y2 - y1 + 1.0f) >= 0.0f))) scr = NEGV;
    }
    ((float4*)boxes)[n * TOPK + r] = make_float4(x1, y1, x2, y2);
    bscores[n * TOPK + r] = scr;
  }
}

__global__ void k_edges(const float* __restrict__ boxes, const float* __restrict__ bscores,
                        unsigned* __restrict__ ecnt, unsigned* __restrict__ edges) {
  if (blockIdx.y > blockIdx.x) return;  // i-chunk entirely >= j-tile: no i<j pairs
  __shared__ float ix1[256], iy1[256], ix2[256], iy2[256], isc[256], iar[256];
  const int n  = blockIdx.z;
  const int ib = blockIdx.y * 256;
  const int tid = threadIdx.x;
  int gi = ib + tid;
  if (gi < TOPK) {
    float4 b = ((const float4*)boxes)[n * TOPK + gi];
    ix1[tid] = b.x; iy1[tid] = b.y; ix2[tid] = b.z; iy2[tid] = b.w;
    isc[tid] = bscores[n * TOPK + gi];
    iar[tid] = (b.z - b.x) * (b.w - b.y);
  } else {
    isc[tid] = NEGV;
  }
  __syncthreads();
  int jg = blockIdx.x * 256 + tid;
  if (jg >= TOPK) return;
  float4 bj = ((const float4*)boxes)[n * TOPK + jg];
  float sj = bscores[n * TOPK + jg];
  if (sj <= NEGV * 0.5f) return;
  float aj = (bj.z - bj.x) * (bj.w - bj.y);
  int tmax = jg - ib; if (tmax > 256) tmax = 256;
  for (int t = 0; t < tmax; ++t) {
    if (isc[t] <= NEGV * 0.5f) continue;
    float ltx = fmaxf(ix1[t], bj.x), lty = fmaxf(iy1[t], bj.y);
    float rbx = fminf(ix2[t], bj.z), rby = fminf(iy2[t], bj.w);
    float wv = fmaxf(rbx - ltx, 0.0f), hv = fmaxf(rby - lty, 0.0f);
    float inter = wv * hv;
    float iou = inter / (iar[t] + aj - inter + 1e-9f);
    if (iou > 0.6f) {
      unsigned pos = atomicAdd(&ecnt[n], 1u);
      if (pos < ECAP) edges[n * ECAP + pos] = ((unsigned)(ib + t) << 10) | (unsigned)jg;
    }
  }
}

__global__ void k_final(const float* __restrict__ boxes, const float* __restrict__ bscores,
                        const unsigned* __restrict__ ecnt, const unsigned* __restrict__ edges,
                        float* __restrict__ out) {
  __shared__ unsigned eds[ECAP];
  __shared__ float ssc[TOPK];
  __shared__ unsigned char kept[TOPK];
  __shared__ int sel[100];
  __shared__ unsigned pfx[128];
  const int n = blockIdx.x;
  const int tid = threadIdx.x;
  unsigned E = ecnt[n]; if (E > ECAP) E = ECAP;
  for (int e = tid; e < TOPK; e += 128) { kept[e] = 1; ssc[e] = bscores[n * TOPK + e]; }
  for (int e = tid; e < (int)E; e += 128) eds[e] = edges[n * ECAP + e];
  if (tid < 100) sel[tid] = -1;
  __syncthreads();
  if (tid == 0) {
    // sort tiny edge list ascending (i-major, j-minor) == greedy processing order
    for (int a = 1; a < (int)E; ++a) {
      unsigned v = eds[a]; int b = a - 1;
      while (b >= 0 && eds[b] > v) { eds[b + 1] = eds[b]; --b; }
      eds[b + 1] = v;
    }
    // exact greedy NMS: kept[i] finalized before any edge (i, j) is applied
    for (int e = 0; e < (int)E; ++e) {
      unsigned i = eds[e] >> 10, j = eds[e] & 1023u;
      if (kept[i]) kept[j] = 0;
    }
  }
  __syncthreads();
  // prefix-sum select first 100 kept (array is score-descending => these are top-100)
  int c = tid;
  unsigned cnt = 0;
  for (int k = 0; k < 8; ++k) {
    int e = c * 8 + k;
    if (e < TOPK && kept[e] && ssc[e] > NEGV * 0.5f) cnt++;
  }
  pfx[c] = cnt;
  __syncthreads();
  if (tid == 0) {
    unsigned acc = 0;
    for (int q = 0; q < 128; ++q) { unsigned t = pfx[q]; pfx[q] = acc; acc += t; }
  }
  __syncthreads();
  unsigned r = pfx[c];
  for (int k = 0; k < 8; ++k) {
    int e = c * 8 + k;
    if (e < TOPK && kept[e] && ssc[e] > NEGV * 0.5f) {
      if (r < 100) sel[r] = e;
      r++;
    }
  }
  __syncthreads();
  for (int k = tid; k < 100; k += 128) {
    int s = sel[k];
    float x1 = 0.f, y1 = 0.f, x2 = 0.f, y2 = 0.f, sc = 0.f, lab = 0.f, fv = 0.f;
    if (s >= 0) {
      float4 b = ((const float4*)boxes)[n * TOPK + s];
      x1 = b.x; y1 = b.y; x2 = b.z; y2 = b.w;
      sc = ssc[s]; lab = 1.0f; fv = 1.0f;
    }
    int o = (n * 100 + k) * 5;
    out[o + 0] = x1; out[o + 1] = y1; out[o + 2] = x2; out[o + 3] = y2; out[o + 4] = sc;
    out[NIMG * 500 + n * 100 + k] = lab;   // labels as 0.0/1.0
    out[NIMG * 600 + n * 100 + k] = fv;    // fvalid as 0.0/1.0
  }
}

extern "C" void kernel_launch(void* const* d_in, const int* in_sizes, int n_in,
                              void* d_out, int out_size, void* d_ws, size_t ws_size,
                              hipStream_t stream) {
  // inputs: 0=locations (unused; grid computed analytically), 1=box_cls,
  //         2=box_regression, 3=centerness, 4=image_sizes
  const float* cls = (const float*)d_in[1];
  const float* reg = (const float*)d_in[2];
  const float* ctr = (const float*)d_in[3];
  const int*   isz = (const int*)d_in[4];
  float* out = (float*)d_out;

  uint8_t* w = (uint8_t*)d_ws;
  unsigned* hist    = (unsigned*)(w + 0);        // 16*4096 u32  = 256 KiB
  float*    cval    = (float*)   (w + 262144);   // 16*4096 f32  = 256 KiB
  unsigned* cidx    = (unsigned*)(w + 524288);   // 16*4096 u32  = 256 KiB
  float*    boxes   = (float*)   (w + 786432);   // 16*1000*4 f32 = 250 KiB
  float*    bscores = (float*)   (w + 1042432);  // 16*1000 f32  = 62.5 KiB
  unsigned* edges   = (unsigned*)(w + 1106432);  // 16*8192 u32  = 512 KiB
  unsigned* bstar   = (unsigned*)(w + 1630720);  // 16 u32
  unsigned* ccount  = (unsigned*)(w + 1630784);  // 16 u32
  unsigned* ecnt    = (unsigned*)(w + 1630848);  // 16 u32

  k_init<<<64, 256, 0, stream>>>(hist, bstar, ccount, ecnt);
  dim3 g1(30, NIMG);  // 30 * 8192 elems >= 243200
  k_hist<<<g1, 256, 0, stream>>>(cls, ctr, hist);
  k_findbin<<<NIMG, 256, 0, stream>>>(hist, bstar);
  k_collect<<<g1, 256, 0, stream>>>(cls, ctr, bstar, ccount, cval, cidx);
  k_sortdecode<<<NIMG, 1024, 0, stream>>>(ccount, cval, cidx, reg, isz, boxes, bscores);
  dim3 g2(4, 4, NIMG);
  k_edges<<<g2, 256, 0, stream>>>(boxes, bscores, ecnt, edges);
  k_final<<<NIMG, 128, 0, stream>>>(boxes, bscores, ecnt, edges, out);
}

// Round 2
// 332.485 us; speedup vs baseline: 1.0152x; 1.0152x over previous
//
#include <hip/hip_runtime.h>
#include <cstdint>

// FCOS post-processor, MI355X. Pipeline:
//  k_init      : zero histogram + counters in ws
//  k_hist      : sm = cand ? sigmoid(cls)*sigmoid(ctr) : NEG ; 4096-bin histogram per image
//                (load-first float4 scan; LDS hist; nonzero-guarded atomic merge)
//  k_findbin   : suffix-scan histogram -> threshold bin b* (top-1000 boundary)
//  k_collect   : recompute sm, collect (val,idx) with bin >= b* via wave-ballot compaction
//  k_sortdecode: bitonic sort 4096 slots (val desc, idx asc == jax top_k tie-break),
//                decode+clip top-1000 boxes, store boxes+scores
//  k_edges     : all pairs i<j with IoU>0.6 -> tiny edge list (conflicts are rare)
//  k_final     : sort edges, exact greedy NMS over edges, prefix-select first 100 kept,
//                write dets/labels/fvalid (labels+fvalid as 0.0/1.0 floats)

#define NIMG 16
#define HH 400
#define WW 608
#define HW 243200
#define NF4 60800   // HW/4
#define TOPK 1000
#define NBINS 4096
#define CCAP 4096
#define ECAP 8192
#define NEGV (-1e9f)

__device__ __forceinline__ float sigm(float x) { return 1.0f / (1.0f + expf(-x)); }

__device__ __forceinline__ int binof(float v) {
  if (!(v > 0.0f)) return 0;
  int b = (int)(v * (float)NBINS);
  return b > (NBINS - 1) ? (NBINS - 1) : b;
}

__global__ void k_init(unsigned* hist, unsigned* bstar, unsigned* ccount, unsigned* ecnt) {
  int i = blockIdx.x * blockDim.x + threadIdx.x;
  int tot = NIMG * NBINS;
  for (int k = i; k < tot; k += gridDim.x * blockDim.x) hist[k] = 0u;
  if (i < NIMG) { bstar[i] = 0u; ccount[i] = 0u; ecnt[i] = 0u; }
}

// 4 float4 per array per thread = 16 elems/thread, 4096 elems/block, 60 blocks/image.
__global__ void k_hist(const float4* __restrict__ cls, const float4* __restrict__ ctr,
                       unsigned* __restrict__ hist) {
  __shared__ unsigned lh[NBINS];
  const int tid = threadIdx.x;
  for (int b = tid; b < NBINS; b += 256) lh[b] = 0u;
  __syncthreads();
  const int n = blockIdx.y;
  const float4* c4 = cls + (size_t)n * NF4;
  const float4* t4 = ctr + (size_t)n * NF4;
  int base = blockIdx.x * 1024;
  float4 cv[4], tv[4];
  bool ok[4];
  #pragma unroll
  for (int e = 0; e < 4; ++e) {
    int i = base + e * 256 + tid;
    ok[e] = (i < NF4);
    if (ok[e]) { cv[e] = c4[i]; tv[e] = t4[i]; }
  }
  #pragma unroll
  for (int e = 0; e < 4; ++e) {
    if (ok[e]) {
      const float* cc = (const float*)&cv[e];
      const float* tt = (const float*)&tv[e];
      #pragma unroll
      for (int k = 0; k < 4; ++k) {
        float sc = sigm(cc[k]);
        float sm = (sc > 0.05f) ? sc * sigm(tt[k]) : NEGV;
        atomicAdd(&lh[binof(sm)], 1u);
      }
    }
  }
  __syncthreads();
  unsigned* gh = hist + n * NBINS;
  for (int b = tid; b < NBINS; b += 256) {
    unsigned v = lh[b];
    if (v) atomicAdd(&gh[b], v);
  }
}

__global__ void k_findbin(const unsigned* __restrict__ hist, unsigned* __restrict__ bstar) {
  __shared__ unsigned chunk[256];
  const int n = blockIdx.x;
  const unsigned* h = hist + n * NBINS;
  unsigned s = 0;
  int c = threadIdx.x;
  for (int k = 0; k < 16; ++k) s += h[c * 16 + k];
  chunk[c] = s;
  __syncthreads();
  if (threadIdx.x == 0) {
    unsigned cum = 0; int bs = 0; int cc;
    for (cc = 255; cc >= 0; --cc) {
      if (cum + chunk[cc] >= TOPK) break;
      cum += chunk[cc];
    }
    if (cc >= 0) {
      int b = cc * 16 + 15;
      for (;;) { cum += h[b]; if (cum >= TOPK || b == cc * 16) break; --b; }
      bs = b;
    }
    bstar[n] = (unsigned)bs;
  }
}

__global__ void k_collect(const float4* __restrict__ cls, const float4* __restrict__ ctr,
                          const unsigned* __restrict__ bstar,
                          unsigned* __restrict__ ccount,
                          float* __restrict__ cval, unsigned* __restrict__ cidx) {
  const int n = blockIdx.y;
  const unsigned bs = bstar[n];
  const int tid = threadIdx.x;
  const int lane = tid & 63;
  const float4* c4 = cls + (size_t)n * NF4;
  const float4* t4 = ctr + (size_t)n * NF4;
  int base = blockIdx.x * 1024;
  float4 cv[4], tv[4];
  bool ok[4];
  #pragma unroll
  for (int e = 0; e < 4; ++e) {
    int i = base + e * 256 + tid;
    ok[e] = (i < NF4);
    if (ok[e]) { cv[e] = c4[i]; tv[e] = t4[i]; }
  }
  #pragma unroll
  for (int e = 0; e < 4; ++e) {
    const float* cc = (const float*)&cv[e];
    const float* tt = (const float*)&tv[e];
    #pragma unroll
    for (int k = 0; k < 4; ++k) {
      float sm = NEGV;
      bool pred = false;
      unsigned gi = 0;
      if (ok[e]) {
        float sc = sigm(cc[k]);
        sm = (sc > 0.05f) ? sc * sigm(tt[k]) : NEGV;
        pred = ((unsigned)binof(sm) >= bs);
        gi = (unsigned)((base + e * 256 + tid) * 4 + k);
      }
      unsigned long long mask = __ballot(pred);
      if (mask) {
        int leader = __ffsll((unsigned long long)mask) - 1;
        unsigned bpos = 0;
        if (lane == leader) bpos = atomicAdd(&ccount[n], (unsigned)__popcll(mask));
        bpos = (unsigned)__shfl((int)bpos, leader);
        if (pred) {
          unsigned p = bpos + (unsigned)__popcll(mask & ((1ull << lane) - 1ull));
          if (p < CCAP) { cval[n * CCAP + p] = sm; cidx[n * CCAP + p] = gi; }
        }
      }
    }
  }
}

__global__ __launch_bounds__(1024) void k_sortdecode(
    const unsigned* __restrict__ ccount,
    const float* __restrict__ cval, const unsigned* __restrict__ cidx,
    const float* __restrict__ reg, const int* __restrict__ isz,
    float* __restrict__ boxes, float* __restrict__ bscores) {
  __shared__ float sv[CCAP];
  __shared__ int   si[CCAP];
  const int n = blockIdx.x;
  const int tid = threadIdx.x;
  unsigned M = ccount[n]; if (M > CCAP) M = CCAP;
  for (int e = tid; e < CCAP; e += 1024) {
    if (e < (int)M) { sv[e] = cval[n * CCAP + e]; si[e] = (int)cidx[n * CCAP + e]; }
    else            { sv[e] = NEGV; si[e] = 0x7fffffff; }
  }
  for (int k = 2; k <= CCAP; k <<= 1) {
    for (int j = k >> 1; j > 0; j >>= 1) {
      __syncthreads();
      for (int e = tid; e < CCAP; e += 1024) {
        int p = e ^ j;
        if (p > e) {
          float v0 = sv[e], v1 = sv[p];
          int   i0 = si[e], i1 = si[p];
          bool before_pe = (v1 > v0) || (v1 == v0 && i1 < i0); // p-elem should precede e-elem
          bool before_ep = (v0 > v1) || (v0 == v1 && i0 < i1);
          bool dir = ((e & k) == 0);
          if (dir ? before_pe : before_ep) {
            sv[e] = v1; sv[p] = v0; si[e] = i1; si[p] = i0;
          }
        }
      }
    }
  }
  __syncthreads();
  const float wmax = (float)(isz[n * 2 + 1] - 1);
  const float hmax = (float)(isz[n * 2 + 0] - 1);
  const float* rg = reg + (size_t)n * 4 * HW;
  for (int r = tid; r < TOPK; r += 1024) {
    float val = sv[r]; int gi = si[r];
    float x1 = 0.f, y1 = 0.f, x2 = 0.f, y2 = 0.f, scr = NEGV;
    if (val > NEGV * 0.5f) {
      int wx = gi % WW, hy = gi / WW;
      float lx = (float)(wx * 8 + 4), ly = (float)(hy * 8 + 4);
      float l  = rg[0 * HW + gi], tt = rg[1 * HW + gi];
      float rr = rg[2 * HW + gi], bb = rg[3 * HW + gi];
      x1 = lx - l;  y1 = ly - tt;  x2 = lx + rr;  y2 = ly + bb;
      x1 = fminf(fmaxf(x1, 0.0f), wmax);
      x2 = fminf(fmaxf(x2, 0.0f), wmax);
      y1 = fminf(fmaxf(y1, 0.0f), hmax);
      y2 = fminf(fmaxf(y2, 0.0f), hmax);
      scr = val;
      if (!(((x2 - x1 + 1.0f) >= 0.0f) && ((y2 - y1 + 1.0f) >= 0.0f))) scr = NEGV;
    }
    ((float4*)boxes)[n * TOPK + r] = make_float4(x1, y1, x2, y2);
    bscores[n * TOPK + r] = scr;
  }
}

__global__ void k_edges(const float* __restrict__ boxes, const float* __restrict__ bscores,
                        unsigned* __restrict__ ecnt, unsigned* __restrict__ edges) {
  if (blockIdx.y > blockIdx.x) return;  // i-chunk entirely >= j-tile: no i<j pairs
  __shared__ float ix1[256], iy1[256], ix2[256], iy2[256], isc[256], iar[256];
  const int n  = blockIdx.z;
  const int ib = blockIdx.y * 256;
  const int tid = threadIdx.x;
  int gi = ib + tid;
  if (gi < TOPK) {
    float4 b = ((const float4*)boxes)[n * TOPK + gi];
    ix1[tid] = b.x; iy1[tid] = b.y; ix2[tid] = b.z; iy2[tid] = b.w;
    isc[tid] = bscores[n * TOPK + gi];
    iar[tid] = (b.z - b.x) * (b.w - b.y);
  } else {
    isc[tid] = NEGV;
  }
  __syncthreads();
  int jg = blockIdx.x * 256 + tid;
  if (jg >= TOPK) return;
  float4 bj = ((const float4*)boxes)[n * TOPK + jg];
  float sj = bscores[n * TOPK + jg];
  if (sj <= NEGV * 0.5f) return;
  float aj = (bj.z - bj.x) * (bj.w - bj.y);
  int tmax = jg - ib; if (tmax > 256) tmax = 256;
  for (int t = 0; t < tmax; ++t) {
    if (isc[t] <= NEGV * 0.5f) continue;
    float ltx = fmaxf(ix1[t], bj.x), lty = fmaxf(iy1[t], bj.y);
    float rbx = fminf(ix2[t], bj.z), rby = fminf(iy2[t], bj.w);
    float wv = fmaxf(rbx - ltx, 0.0f), hv = fmaxf(rby - lty, 0.0f);
    float inter = wv * hv;
    float iou = inter / (iar[t] + aj - inter + 1e-9f);
    if (iou > 0.6f) {
      unsigned pos = atomicAdd(&ecnt[n], 1u);
      if (pos < ECAP) edges[n * ECAP + pos] = ((unsigned)(ib + t) << 10) | (unsigned)jg;
    }
  }
}

__global__ void k_final(const float* __restrict__ boxes, const float* __restrict__ bscores,
                        const unsigned* __restrict__ ecnt, const unsigned* __restrict__ edges,
                        float* __restrict__ out) {
  __shared__ unsigned eds[ECAP];
  __shared__ float ssc[TOPK];
  __shared__ unsigned char kept[TOPK];
  __shared__ int sel[100];
  __shared__ unsigned pfx[128];
  const int n = blockIdx.x;
  const int tid = threadIdx.x;
  unsigned E = ecnt[n]; if (E > ECAP) E = ECAP;
  for (int e = tid; e < TOPK; e += 128) { kept[e] = 1; ssc[e] = bscores[n * TOPK + e]; }
  for (int e = tid; e < (int)E; e += 128) eds[e] = edges[n * ECAP + e];
  if (tid < 100) sel[tid] = -1;
  __syncthreads();
  if (tid == 0) {
    // sort tiny edge list ascending (i-major, j-minor) == greedy processing order
    for (int a = 1; a < (int)E; ++a) {
      unsigned v = eds[a]; int b = a - 1;
      while (b >= 0 && eds[b] > v) { eds[b + 1] = eds[b]; --b; }
      eds[b + 1] = v;
    }
    // exact greedy NMS: kept[i] finalized before any edge (i, j) is applied
    for (int e = 0; e < (int)E; ++e) {
      unsigned i = eds[e] >> 10, j = eds[e] & 1023u;
      if (kept[i]) kept[j] = 0;
    }
  }
  __syncthreads();
  // prefix-sum select first 100 kept (array is score-descending => these are top-100)
  int c = tid;
  unsigned cnt = 0;
  for (int k = 0; k < 8; ++k) {
    int e = c * 8 + k;
    if (e < TOPK && kept[e] && ssc[e] > NEGV * 0.5f) cnt++;
  }
  pfx[c] = cnt;
  __syncthreads();
  if (tid == 0) {
    unsigned acc = 0;
    for (int q = 0; q < 128; ++q) { unsigned t = pfx[q]; pfx[q] = acc; acc += t; }
  }
  __syncthreads();
  unsigned r = pfx[c];
  for (int k = 0; k < 8; ++k) {
    int e = c * 8 + k;
    if (e < TOPK && kept[e] && ssc[e] > NEGV * 0.5f) {
      if (r < 100) sel[r] = e;
      r++;
    }
  }
  __syncthreads();
  for (int k = tid; k < 100; k += 128) {
    int s = sel[k];
    float x1 = 0.f, y1 = 0.f, x2 = 0.f, y2 = 0.f, sc = 0.f, lab = 0.f, fv = 0.f;
    if (s >= 0) {
      float4 b = ((const float4*)boxes)[n * TOPK + s];
      x1 = b.x; y1 = b.y; x2 = b.z; y2 = b.w;
      sc = ssc[s]; lab = 1.0f; fv = 1.0f;
    }
    int o = (n * 100 + k) * 5;
    out[o + 0] = x1; out[o + 1] = y1; out[o + 2] = x2; out[o + 3] = y2; out[o + 4] = sc;
    out[NIMG * 500 + n * 100 + k] = lab;   // labels as 0.0/1.0
    out[NIMG * 600 + n * 100 + k] = fv;    // fvalid as 0.0/1.0
  }
}

extern "C" void kernel_launch(void* const* d_in, const int* in_sizes, int n_in,
                              void* d_out, int out_size, void* d_ws, size_t ws_size,
                              hipStream_t stream) {
  // inputs: 0=locations (unused; grid computed analytically), 1=box_cls,
  //         2=box_regression, 3=centerness, 4=image_sizes
  const float4* cls4 = (const float4*)d_in[1];
  const float*  reg  = (const float*)d_in[2];
  const float4* ctr4 = (const float4*)d_in[3];
  const int*    isz  = (const int*)d_in[4];
  float* out = (float*)d_out;

  uint8_t* w = (uint8_t*)d_ws;
  unsigned* hist    = (unsigned*)(w + 0);        // 16*4096 u32  = 256 KiB
  float*    cval    = (float*)   (w + 262144);   // 16*4096 f32  = 256 KiB
  unsigned* cidx    = (unsigned*)(w + 524288);   // 16*4096 u32  = 256 KiB
  float*    boxes   = (float*)   (w + 786432);   // 16*1000*4 f32 = 250 KiB
  float*    bscores = (float*)   (w + 1042432);  // 16*1000 f32  = 62.5 KiB
  unsigned* edges   = (unsigned*)(w + 1106432);  // 16*8192 u32  = 512 KiB
  unsigned* bstar   = (unsigned*)(w + 1630720);  // 16 u32
  unsigned* ccount  = (unsigned*)(w + 1630784);  // 16 u32
  unsigned* ecnt    = (unsigned*)(w + 1630848);  // 16 u32

  k_init<<<64, 256, 0, stream>>>(hist, bstar, ccount, ecnt);
  dim3 g1(60, NIMG);  // 60 blocks * 1024 float4 >= 60800 float4 per image
  k_hist<<<g1, 256, 0, stream>>>(cls4, ctr4, hist);
  k_findbin<<<NIMG, 256, 0, stream>>>(hist, bstar);
  k_collect<<<g1, 256, 0, stream>>>(cls4, ctr4, bstar, ccount, cval, cidx);
  k_sortdecode<<<NIMG, 1024, 0, stream>>>(ccount, cval, cidx, reg, isz, boxes, bscores);
  dim3 g2(4, 4, NIMG);
  k_edges<<<g2, 256, 0, stream>>>(boxes, bscores, ecnt, edges);
  k_final<<<NIMG, 128, 0, stream>>>(boxes, bscores, ecnt, edges, out);
}

// Round 3
// 151.755 us; speedup vs baseline: 2.2242x; 2.1909x over previous
//
#include <hip/hip_runtime.h>
#include <cstdint>

// FCOS post-processor, MI355X — round 3: ZERO device-scope atomics in hot path.
// Theory: per-XCD L2 non-coherence forces global atomics to the memory-side
// coherence point; same-address atomic-with-return chains serialized k_collect
// at ~167us and 2.5M merge atomics pinned k_hist at ~145us. All replaced by
// private per-block slices + block-local LDS compaction + deterministic gather.
//
//  k_scan      : sm = cand ? sig(cls)*sig(ctr) : NEG ; per-block 4096-bin LDS hist
//                -> private global slice [n][60][4096] (no atomics)
//  k_findbin   : reduce 60 slices -> per-image hist -> suffix-scan -> b*
//  k_collect2  : recompute sm, keep bin>=b*, LDS-compact -> partition [n][blk][72]+cnt
//  k_sortdecode: gather partitions (cnt-prefix), bitonic sort 2048 (val desc, idx asc
//                == jax top_k tie-break), decode+clip top-1000 -> boxes/scores
//  k_edges     : all pairs i<j with IoU>0.6 -> tiny edge list (conflicts rare)
//  k_final     : sort edges, exact greedy NMS, prefix-select first 100 kept, write out

#define NIMG 16
#define HH 400
#define WW 608
#define HW 243200
#define NF4 60800         // HW/4
#define TOPK 1000
#define NBINS 4096
#define SCAN_BLOCKS 60    // per image
#define SCAN_THREADS 256
#define F4_PER_BLOCK 1024 // 60*1024*4 = 245760 >= 243200
#define RSLOTS 72         // partition slots per scan block (~17 expected, 72 = +13 sigma)
#define SPILL 32
#define CSLOTS (SCAN_BLOCKS * RSLOTS + SPILL)  // 4352 per image
#define CAP2 2048
#define ECAP 8192
#define NEGV (-1e9f)

__device__ __forceinline__ float sigm(float x) { return 1.0f / (1.0f + expf(-x)); }

__device__ __forceinline__ int binof(float v) {
  if (!(v > 0.0f)) return 0;
  int b = (int)(v * (float)NBINS);
  return b > (NBINS - 1) ? (NBINS - 1) : b;
}

// SLICES=true : write LDS hist to private slice (no atomics)
// SLICES=false: fallback (small ws) — atomic merge into per-image hist
template <bool SLICES>
__global__ __launch_bounds__(SCAN_THREADS) void k_scan(
    const float4* __restrict__ cls, const float4* __restrict__ ctr,
    unsigned* __restrict__ hist) {
  __shared__ unsigned lh[NBINS];
  const int tid = threadIdx.x;
  for (int b = tid; b < NBINS; b += SCAN_THREADS) lh[b] = 0u;
  __syncthreads();
  const int n = blockIdx.y;
  const float4* c4 = cls + (size_t)n * NF4;
  const float4* t4 = ctr + (size_t)n * NF4;
  int base = blockIdx.x * F4_PER_BLOCK;
  float4 cv[4], tv[4];
  bool ok[4];
#pragma unroll
  for (int e = 0; e < 4; ++e) {
    int i = base + e * SCAN_THREADS + tid;
    ok[e] = (i < NF4);
    if (ok[e]) { cv[e] = c4[i]; tv[e] = t4[i]; }
  }
#pragma unroll
  for (int e = 0; e < 4; ++e) {
    if (ok[e]) {
      const float* cc = (const float*)&cv[e];
      const float* tt = (const float*)&tv[e];
#pragma unroll
      for (int k = 0; k < 4; ++k) {
        float sc = sigm(cc[k]);
        float sm = (sc > 0.05f) ? sc * sigm(tt[k]) : NEGV;
        atomicAdd(&lh[binof(sm)], 1u);  // LDS atomic: CU-local, cheap
      }
    }
  }
  __syncthreads();
  if (SLICES) {
    unsigned* gh = hist + ((size_t)n * SCAN_BLOCKS + blockIdx.x) * NBINS;
    for (int b = tid; b < NBINS; b += SCAN_THREADS) gh[b] = lh[b];
  } else {
    unsigned* gh = hist + (size_t)n * NBINS;
    for (int b = tid; b < NBINS; b += SCAN_THREADS) {
      unsigned v = lh[b];
      if (v) atomicAdd(&gh[b], v);
    }
  }
}

template <bool SLICES>
__global__ __launch_bounds__(1024) void k_findbin(
    const unsigned* __restrict__ hist, unsigned* __restrict__ bstar) {
  __shared__ unsigned h[NBINS];
  __shared__ unsigned chunk[256];
  const int n = blockIdx.x;
  const int tid = threadIdx.x;
  if (SLICES) {
    uint4 s = make_uint4(0u, 0u, 0u, 0u);
    const uint4* base = (const uint4*)(hist + (size_t)n * SCAN_BLOCKS * NBINS);
    for (int b = 0; b < SCAN_BLOCKS; ++b) {
      uint4 v = base[b * (NBINS / 4) + tid];
      s.x += v.x; s.y += v.y; s.z += v.z; s.w += v.w;
    }
    ((uint4*)h)[tid] = s;
  } else {
    const unsigned* gh = hist + (size_t)n * NBINS;
    for (int b = tid; b < NBINS; b += 1024) h[b] = gh[b];
  }
  __syncthreads();
  if (tid < 256) {
    unsigned s = 0;
    for (int k = 0; k < 16; ++k) s += h[tid * 16 + k];
    chunk[tid] = s;
  }
  __syncthreads();
  if (tid == 0) {
    unsigned cum = 0; int bs = 0; int cc;
    for (cc = 255; cc >= 0; --cc) {
      if (cum + chunk[cc] >= TOPK) break;
      cum += chunk[cc];
    }
    if (cc >= 0) {
      int b = cc * 16 + 15;
      for (;;) { cum += h[b]; if (cum >= TOPK || b == cc * 16) break; --b; }
      bs = b;
    }
    bstar[n] = (unsigned)bs;
  }
}

__global__ __launch_bounds__(SCAN_THREADS) void k_collect2(
    const float4* __restrict__ cls, const float4* __restrict__ ctr,
    const unsigned* __restrict__ bstar,
    float* __restrict__ cval, unsigned* __restrict__ cidx,
    unsigned* __restrict__ cnt, unsigned* __restrict__ spill) {
  __shared__ float sval[RSLOTS];
  __shared__ unsigned sidx[RSLOTS];
  __shared__ unsigned scnt;
  const int n = blockIdx.y;
  const int tid = threadIdx.x;
  if (tid == 0) scnt = 0u;
  __syncthreads();
  const unsigned bs = bstar[n];
  const float4* c4 = cls + (size_t)n * NF4;
  const float4* t4 = ctr + (size_t)n * NF4;
  int base = blockIdx.x * F4_PER_BLOCK;
  float4 cv[4], tv[4];
  bool ok[4];
#pragma unroll
  for (int e = 0; e < 4; ++e) {
    int i = base + e * SCAN_THREADS + tid;
    ok[e] = (i < NF4);
    if (ok[e]) { cv[e] = c4[i]; tv[e] = t4[i]; }
  }
#pragma unroll
  for (int e = 0; e < 4; ++e) {
    if (ok[e]) {
      const float* cc = (const float*)&cv[e];
      const float* tt = (const float*)&tv[e];
#pragma unroll
      for (int k = 0; k < 4; ++k) {
        float sc = sigm(cc[k]);
        float sm = (sc > 0.05f) ? sc * sigm(tt[k]) : NEGV;
        if (sm > NEGV * 0.5f && (unsigned)binof(sm) >= bs) {
          unsigned gi = (unsigned)((base + e * SCAN_THREADS + tid) * 4 + k);
          unsigned p = atomicAdd(&scnt, 1u);  // LDS atomic
          if (p < RSLOTS) {
            sval[p] = sm; sidx[p] = gi;
          } else {  // overflow: rare; device atomic only here
            unsigned q = atomicAdd(&spill[n], 1u);
            if (q < SPILL) {
              cval[n * CSLOTS + SCAN_BLOCKS * RSLOTS + q] = sm;
              cidx[n * CSLOTS + SCAN_BLOCKS * RSLOTS + q] = gi;
            }
          }
        }
      }
    }
  }
  __syncthreads();
  unsigned m = scnt; if (m > RSLOTS) m = RSLOTS;
  if (tid < m) {
    cval[n * CSLOTS + blockIdx.x * RSLOTS + tid] = sval[tid];
    cidx[n * CSLOTS + blockIdx.x * RSLOTS + tid] = sidx[tid];
  }
  if (tid == 0) cnt[n * SCAN_BLOCKS + blockIdx.x] = m;
}

__global__ __launch_bounds__(1024) void k_sortdecode(
    const unsigned* __restrict__ cnt, const unsigned* __restrict__ spill,
    const float* __restrict__ cval, const unsigned* __restrict__ cidx,
    const float* __restrict__ reg, const int* __restrict__ isz,
    float* __restrict__ boxes, float* __restrict__ bscores) {
  __shared__ float sv[CAP2];
  __shared__ int si[CAP2];
  __shared__ unsigned offs[SCAN_BLOCKS + 1];
  const int n = blockIdx.x;
  const int tid = threadIdx.x;
  if (tid == 0) {
    unsigned acc = 0;
    for (int b = 0; b < SCAN_BLOCKS; ++b) { offs[b] = acc; acc += cnt[n * SCAN_BLOCKS + b]; }
    offs[SCAN_BLOCKS] = acc;
  }
  for (int e = tid; e < CAP2; e += 1024) { sv[e] = NEGV; si[e] = 0x7fffffff; }
  __syncthreads();
  // gather partitions into dense [0..M); block order irrelevant (total-order sort next)
  for (int s = tid; s < SCAN_BLOCKS * RSLOTS; s += 1024) {
    int r = s / RSLOTS, k = s % RSLOTS;
    unsigned c = offs[r + 1] - offs[r];
    if ((unsigned)k < c) {
      unsigned d = offs[r] + (unsigned)k;
      if (d < CAP2) { sv[d] = cval[n * CSLOTS + s]; si[d] = (int)cidx[n * CSLOTS + s]; }
    }
  }
  {
    unsigned sp = spill[n]; if (sp > SPILL) sp = SPILL;
    for (unsigned k = tid; k < sp; k += 1024) {
      unsigned d = offs[SCAN_BLOCKS] + k;
      if (d < CAP2) {
        sv[d] = cval[n * CSLOTS + SCAN_BLOCKS * RSLOTS + k];
        si[d] = (int)cidx[n * CSLOTS + SCAN_BLOCKS * RSLOTS + k];
      }
    }
  }
  // bitonic sort: (val desc, idx asc) — matches jax.lax.top_k tie-break
  for (int k = 2; k <= CAP2; k <<= 1) {
    for (int j = k >> 1; j > 0; j >>= 1) {
      __syncthreads();
      for (int e = tid; e < CAP2; e += 1024) {
        int p = e ^ j;
        if (p > e) {
          float v0 = sv[e], v1 = sv[p];
          int i0 = si[e], i1 = si[p];
          bool before_pe = (v1 > v0) || (v1 == v0 && i1 < i0);
          bool before_ep = (v0 > v1) || (v0 == v1 && i0 < i1);
          bool dir = ((e & k) == 0);
          if (dir ? before_pe : before_ep) {
            sv[e] = v1; sv[p] = v0; si[e] = i1; si[p] = i0;
          }
        }
      }
    }
  }
  __syncthreads();
  const float wmax = (float)(isz[n * 2 + 1] - 1);
  const float hmax = (float)(isz[n * 2 + 0] - 1);
  const float* rg = reg + (size_t)n * 4 * HW;
  for (int r = tid; r < TOPK; r += 1024) {
    float val = sv[r]; int gi = si[r];
    float x1 = 0.f, y1 = 0.f, x2 = 0.f, y2 = 0.f, scr = NEGV;
    if (val > NEGV * 0.5f) {
      int wx = gi % WW, hy = gi / WW;
      float lx = (float)(wx * 8 + 4), ly = (float)(hy * 8 + 4);
      float l = rg[0 * HW + gi], tt = rg[1 * HW + gi];
      float rr = rg[2 * HW + gi], bb = rg[3 * HW + gi];
      x1 = lx - l;  y1 = ly - tt;  x2 = lx + rr;  y2 = ly + bb;
      x1 = fminf(fmaxf(x1, 0.0f), wmax);
      x2 = fminf(fmaxf(x2, 0.0f), wmax);
      y1 = fminf(fmaxf(y1, 0.0f), hmax);
      y2 = fminf(fmaxf(y2, 0.0f), hmax);
      scr = val;
      if (!(((x2 - x1 + 1.0f) >= 0.0f) && ((y2 - y1 + 1.0f) >= 0.0f))) scr = NEGV;
    }
    ((float4*)boxes)[n * TOPK + r] = make_float4(x1, y1, x2, y2);
    bscores[n * TOPK + r] = scr;
  }
}

__global__ void k_edges(const float* __restrict__ boxes, const float* __restrict__ bscores,
                        unsigned* __restrict__ ecnt, unsigned* __restrict__ edges) {
  if (blockIdx.y > blockIdx.x) return;
  __shared__ float ix1[256], iy1[256], ix2[256], iy2[256], isc[256], iar[256];
  const int n = blockIdx.z;
  const int ib = blockIdx.y * 256;
  const int tid = threadIdx.x;
  int gi = ib + tid;
  if (gi < TOPK) {
    float4 b = ((const float4*)boxes)[n * TOPK + gi];
    ix1[tid] = b.x; iy1[tid] = b.y; ix2[tid] = b.z; iy2[tid] = b.w;
    isc[tid] = bscores[n * TOPK + gi];
    iar[tid] = (b.z - b.x) * (b.w - b.y);
  } else {
    isc[tid] = NEGV;
  }
  __syncthreads();
  int jg = blockIdx.x * 256 + tid;
  if (jg >= TOPK) return;
  float4 bj = ((const float4*)boxes)[n * TOPK + jg];
  float sj = bscores[n * TOPK + jg];
  if (sj <= NEGV * 0.5f) return;
  float aj = (bj.z - bj.x) * (bj.w - bj.y);
  int tmax = jg - ib; if (tmax > 256) tmax = 256;
  for (int t = 0; t < tmax; ++t) {
    if (isc[t] <= NEGV * 0.5f) continue;
    float ltx = fmaxf(ix1[t], bj.x), lty = fmaxf(iy1[t], bj.y);
    float rbx = fminf(ix2[t], bj.z), rby = fminf(iy2[t], bj.w);
    float wv = fmaxf(rbx - ltx, 0.0f), hv = fmaxf(rby - lty, 0.0f);
    float inter = wv * hv;
    float iou = inter / (iar[t] + aj - inter + 1e-9f);
    if (iou > 0.6f) {
      unsigned pos = atomicAdd(&ecnt[n], 1u);  // rare (~tens/image)
      if (pos < ECAP) edges[n * ECAP + pos] = ((unsigned)(ib + t) << 10) | (unsigned)jg;
    }
  }
}

__global__ void k_final(const float* __restrict__ boxes, const float* __restrict__ bscores,
                        const unsigned* __restrict__ ecnt, const unsigned* __restrict__ edges,
                        float* __restrict__ out) {
  __shared__ unsigned eds[ECAP];
  __shared__ float ssc[TOPK];
  __shared__ unsigned char kept[TOPK];
  __shared__ int sel[100];
  __shared__ unsigned pfx[128];
  const int n = blockIdx.x;
  const int tid = threadIdx.x;
  unsigned E = ecnt[n]; if (E > ECAP) E = ECAP;
  for (int e = tid; e < TOPK; e += 128) { kept[e] = 1; ssc[e] = bscores[n * TOPK + e]; }
  for (int e = tid; e < (int)E; e += 128) eds[e] = edges[n * ECAP + e];
  if (tid < 100) sel[tid] = -1;
  __syncthreads();
  if (tid == 0) {
    for (int a = 1; a < (int)E; ++a) {
      unsigned v = eds[a]; int b = a - 1;
      while (b >= 0 && eds[b] > v) { eds[b + 1] = eds[b]; --b; }
      eds[b + 1] = v;
    }
    for (int e = 0; e < (int)E; ++e) {
      unsigned i = eds[e] >> 10, j = eds[e] & 1023u;
      if (kept[i]) kept[j] = 0;
    }
  }
  __syncthreads();
  int c = tid;
  unsigned cntk = 0;
  for (int k = 0; k < 8; ++k) {
    int e = c * 8 + k;
    if (e < TOPK && kept[e] && ssc[e] > NEGV * 0.5f) cntk++;
  }
  pfx[c] = cntk;
  __syncthreads();
  if (tid == 0) {
    unsigned acc = 0;
    for (int q = 0; q < 128; ++q) { unsigned t = pfx[q]; pfx[q] = acc; acc += t; }
  }
  __syncthreads();
  unsigned r = pfx[c];
  for (int k = 0; k < 8; ++k) {
    int e = c * 8 + k;
    if (e < TOPK && kept[e] && ssc[e] > NEGV * 0.5f) {
      if (r < 100) sel[r] = e;
      r++;
    }
  }
  __syncthreads();
  for (int k = tid; k < 100; k += 128) {
    int s = sel[k];
    float x1 = 0.f, y1 = 0.f, x2 = 0.f, y2 = 0.f, sc = 0.f, lab = 0.f, fv = 0.f;
    if (s >= 0) {
      float4 b = ((const float4*)boxes)[n * TOPK + s];
      x1 = b.x; y1 = b.y; x2 = b.z; y2 = b.w;
      sc = ssc[s]; lab = 1.0f; fv = 1.0f;
    }
    int o = (n * 100 + k) * 5;
    out[o + 0] = x1; out[o + 1] = y1; out[o + 2] = x2; out[o + 3] = y2; out[o + 4] = sc;
    out[NIMG * 500 + n * 100 + k] = lab;
    out[NIMG * 600 + n * 100 + k] = fv;
  }
}

extern "C" void kernel_launch(void* const* d_in, const int* in_sizes, int n_in,
                              void* d_out, int out_size, void* d_ws, size_t ws_size,
                              hipStream_t stream) {
  const float4* cls4 = (const float4*)d_in[1];
  const float* reg = (const float*)d_in[2];
  const float4* ctr4 = (const float4*)d_in[3];
  const int* isz = (const int*)d_in[4];
  float* out = (float*)d_out;
  uint8_t* w = (uint8_t*)d_ws;

  const size_t slicesA = (size_t)NIMG * SCAN_BLOCKS * NBINS * 4;  // 15,728,640
  const size_t histB = (size_t)NIMG * NBINS * 4;                  // 262,144
  const size_t tail = (size_t)NIMG * CSLOTS * 4 * 2               // cval+cidx
                    + (size_t)NIMG * SCAN_BLOCKS * 4              // cnt
                    + (size_t)NIMG * TOPK * 4 * 4                 // boxes
                    + (size_t)NIMG * TOPK * 4                     // bscores
                    + (size_t)NIMG * ECAP * 4                     // edges
                    + 64 + 64 + 64;                               // spill, ecnt, bstar
  const bool tierA = ws_size >= slicesA + tail;  // constant per session -> graph-safe

  unsigned* hist = (unsigned*)w;
  uint8_t* p = w + (tierA ? slicesA : histB);
  float* cval = (float*)p;      p += (size_t)NIMG * CSLOTS * 4;
  unsigned* cidx = (unsigned*)p; p += (size_t)NIMG * CSLOTS * 4;
  unsigned* cnt = (unsigned*)p;  p += (size_t)NIMG * SCAN_BLOCKS * 4;
  float* boxes = (float*)p;      p += (size_t)NIMG * TOPK * 4 * 4;
  float* bscores = (float*)p;    p += (size_t)NIMG * TOPK * 4;
  unsigned* edges = (unsigned*)p; p += (size_t)NIMG * ECAP * 4;
  unsigned* spill = (unsigned*)p; p += 64;
  unsigned* ecnt = (unsigned*)p;  p += 64;
  unsigned* bstar = (unsigned*)p;

  hipMemsetAsync(spill, 0, 128, stream);  // spill[16] + ecnt[16] (adjacent)
  if (!tierA) hipMemsetAsync(hist, 0, histB, stream);

  dim3 g1(SCAN_BLOCKS, NIMG);
  if (tierA) {
    k_scan<true><<<g1, SCAN_THREADS, 0, stream>>>(cls4, ctr4, hist);
    k_findbin<true><<<NIMG, 1024, 0, stream>>>(hist, bstar);
  } else {
    k_scan<false><<<g1, SCAN_THREADS, 0, stream>>>(cls4, ctr4, hist);
    k_findbin<false><<<NIMG, 1024, 0, stream>>>(hist, bstar);
  }
  k_collect2<<<g1, SCAN_THREADS, 0, stream>>>(cls4, ctr4, bstar, cval, cidx, cnt, spill);
  k_sortdecode<<<NIMG, 1024, 0, stream>>>(cnt, spill, cval, cidx, reg, isz, boxes, bscores);
  dim3 g2(4, 4, NIMG);
  k_edges<<<g2, 256, 0, stream>>>(boxes, bscores, ecnt, edges);
  k_final<<<NIMG, 128, 0, stream>>>(boxes, bscores, ecnt, edges, out);
}

// Round 4
// 108.564 us; speedup vs baseline: 3.1091x; 1.3978x over previous
//
#include <hip/hip_runtime.h>
#include <cstdint>

// FCOS post-processor, MI355X — round 4.
// R3 postmortem: bitonic sort (66 barrier passes, 16 blocks) and tile-serial
// edge extraction (256-deep serial loops, 160 blocks) were each ~52us of pure
// latency. Replaced by barrier-free rank-by-counting (u64 monotone keys) and
// pair-parallel IoU over staged LDS boxes.
//
//  k_scan      : sm = cand ? sig(cls)*sig(ctr) : NEG ; per-block 4096-bin LDS hist
//                -> private global slice [n][60][4096] (no device atomics)
//  k_findbin   : reduce slices -> suffix-scan -> b* ; prefill boxes=0/bscores=NEG
//  k_collect2  : recompute sm, keep bin>=b*, LDS-compact -> partition [n][blk][72]+cnt
//  k_rank      : gather partitions, pack u64 keys, rank = count(keys > mine),
//                rank<1000 -> decode+clip -> boxes[rank], bscores[rank]
//  k_edges     : stage 1000 boxes in LDS; pair-parallel IoU>0.6 -> edge list
//  k_final     : sort edges, exact greedy NMS, prefix-select first 100 kept, write out

#define NIMG 16
#define HH 400
#define WW 608
#define HW 243200
#define NF4 60800         // HW/4
#define TOPK 1000
#define NBINS 4096
#define SCAN_BLOCKS 60    // per image
#define SCAN_THREADS 256
#define F4_PER_BLOCK 1024 // 60*1024*4 = 245760 >= 243200
#define RSLOTS 72         // partition slots per scan block (~17 expected)
#define SPILL 32
#define CSLOTS (SCAN_BLOCKS * RSLOTS + SPILL)  // 4352 per image
#define MCAP 2048
#define RANK_BLOCKS 8     // per image, 128 threads each -> 1024 rankers
#define EBLK 32           // edge blocks per image
#define ECAP 8192
#define NEGV (-1e9f)

__device__ __forceinline__ float sigm(float x) { return 1.0f / (1.0f + expf(-x)); }

__device__ __forceinline__ int binof(float v) {
  if (!(v > 0.0f)) return 0;
  int b = (int)(v * (float)NBINS);
  return b > (NBINS - 1) ? (NBINS - 1) : b;
}

template <bool SLICES>
__global__ __launch_bounds__(SCAN_THREADS) void k_scan(
    const float4* __restrict__ cls, const float4* __restrict__ ctr,
    unsigned* __restrict__ hist) {
  __shared__ unsigned lh[NBINS];
  const int tid = threadIdx.x;
  for (int b = tid; b < NBINS; b += SCAN_THREADS) lh[b] = 0u;
  __syncthreads();
  const int n = blockIdx.y;
  const float4* c4 = cls + (size_t)n * NF4;
  const float4* t4 = ctr + (size_t)n * NF4;
  int base = blockIdx.x * F4_PER_BLOCK;
  float4 cv[4], tv[4];
  bool ok[4];
#pragma unroll
  for (int e = 0; e < 4; ++e) {
    int i = base + e * SCAN_THREADS + tid;
    ok[e] = (i < NF4);
    if (ok[e]) { cv[e] = c4[i]; tv[e] = t4[i]; }
  }
#pragma unroll
  for (int e = 0; e < 4; ++e) {
    if (ok[e]) {
      const float* cc = (const float*)&cv[e];
      const float* tt = (const float*)&tv[e];
#pragma unroll
      for (int k = 0; k < 4; ++k) {
        float sc = sigm(cc[k]);
        float sm = (sc > 0.05f) ? sc * sigm(tt[k]) : NEGV;
        atomicAdd(&lh[binof(sm)], 1u);  // LDS atomic: CU-local
      }
    }
  }
  __syncthreads();
  if (SLICES) {
    unsigned* gh = hist + ((size_t)n * SCAN_BLOCKS + blockIdx.x) * NBINS;
    for (int b = tid; b < NBINS; b += SCAN_THREADS) gh[b] = lh[b];
  } else {
    unsigned* gh = hist + (size_t)n * NBINS;
    for (int b = tid; b < NBINS; b += SCAN_THREADS) {
      unsigned v = lh[b];
      if (v) atomicAdd(&gh[b], v);
    }
  }
}

template <bool SLICES>
__global__ __launch_bounds__(1024) void k_findbin(
    const unsigned* __restrict__ hist, unsigned* __restrict__ bstar,
    float4* __restrict__ boxes, float* __restrict__ bscores) {
  __shared__ unsigned h[NBINS];
  __shared__ unsigned chunk[256];
  const int n = blockIdx.x;
  const int tid = threadIdx.x;
  if (SLICES) {
    uint4 s = make_uint4(0u, 0u, 0u, 0u);
    const uint4* base = (const uint4*)(hist + (size_t)n * SCAN_BLOCKS * NBINS);
    for (int b = 0; b < SCAN_BLOCKS; ++b) {
      uint4 v = base[b * (NBINS / 4) + tid];
      s.x += v.x; s.y += v.y; s.z += v.z; s.w += v.w;
    }
    ((uint4*)h)[tid] = s;
  } else {
    const unsigned* gh = hist + (size_t)n * NBINS;
    for (int b = tid; b < NBINS; b += 1024) h[b] = gh[b];
  }
  // prefill output background (k_rank overwrites ranks < M)
  if (tid < TOPK) {
    boxes[n * TOPK + tid] = make_float4(0.f, 0.f, 0.f, 0.f);
    bscores[n * TOPK + tid] = NEGV;
  }
  __syncthreads();
  if (tid < 256) {
    unsigned s = 0;
    for (int k = 0; k < 16; ++k) s += h[tid * 16 + k];
    chunk[tid] = s;
  }
  __syncthreads();
  if (tid == 0) {
    unsigned cum = 0; int bs = 0; int cc;
    for (cc = 255; cc >= 0; --cc) {
      if (cum + chunk[cc] >= TOPK) break;
      cum += chunk[cc];
    }
    if (cc >= 0) {
      int b = cc * 16 + 15;
      for (;;) { cum += h[b]; if (cum >= TOPK || b == cc * 16) break; --b; }
      bs = b;
    }
    bstar[n] = (unsigned)bs;
  }
}

__global__ __launch_bounds__(SCAN_THREADS) void k_collect2(
    const float4* __restrict__ cls, const float4* __restrict__ ctr,
    const unsigned* __restrict__ bstar,
    float* __restrict__ cval, unsigned* __restrict__ cidx,
    unsigned* __restrict__ cnt, unsigned* __restrict__ spill) {
  __shared__ float sval[RSLOTS];
  __shared__ unsigned sidx[RSLOTS];
  __shared__ unsigned scnt;
  const int n = blockIdx.y;
  const int tid = threadIdx.x;
  if (tid == 0) scnt = 0u;
  __syncthreads();
  const unsigned bs = bstar[n];
  const float4* c4 = cls + (size_t)n * NF4;
  const float4* t4 = ctr + (size_t)n * NF4;
  int base = blockIdx.x * F4_PER_BLOCK;
  float4 cv[4], tv[4];
  bool ok[4];
#pragma unroll
  for (int e = 0; e < 4; ++e) {
    int i = base + e * SCAN_THREADS + tid;
    ok[e] = (i < NF4);
    if (ok[e]) { cv[e] = c4[i]; tv[e] = t4[i]; }
  }
#pragma unroll
  for (int e = 0; e < 4; ++e) {
    if (ok[e]) {
      const float* cc = (const float*)&cv[e];
      const float* tt = (const float*)&tv[e];
#pragma unroll
      for (int k = 0; k < 4; ++k) {
        float sc = sigm(cc[k]);
        float sm = (sc > 0.05f) ? sc * sigm(tt[k]) : NEGV;
        if (sm > NEGV * 0.5f && (unsigned)binof(sm) >= bs) {
          unsigned gi = (unsigned)((base + e * SCAN_THREADS + tid) * 4 + k);
          unsigned p = atomicAdd(&scnt, 1u);  // LDS atomic
          if (p < RSLOTS) {
            sval[p] = sm; sidx[p] = gi;
          } else {
            unsigned q = atomicAdd(&spill[n], 1u);  // rare overflow only
            if (q < SPILL) {
              cval[n * CSLOTS + SCAN_BLOCKS * RSLOTS + q] = sm;
              cidx[n * CSLOTS + SCAN_BLOCKS * RSLOTS + q] = gi;
            }
          }
        }
      }
    }
  }
  __syncthreads();
  unsigned m = scnt; if (m > RSLOTS) m = RSLOTS;
  if (tid < m) {
    cval[n * CSLOTS + blockIdx.x * RSLOTS + tid] = sval[tid];
    cidx[n * CSLOTS + blockIdx.x * RSLOTS + tid] = sidx[tid];
  }
  if (tid == 0) cnt[n * SCAN_BLOCKS + blockIdx.x] = m;
}

// Rank-by-counting: key = (fbits(val)<<32)|~idx is monotone for (val desc, idx asc)
// == jax.lax.top_k order. rank = #{keys > mine}; ranks are distinct -> direct scatter.
__global__ __launch_bounds__(128) void k_rank(
    const unsigned* __restrict__ cnt, const unsigned* __restrict__ spill,
    const float* __restrict__ cval, const unsigned* __restrict__ cidx,
    const float* __restrict__ reg, const int* __restrict__ isz,
    float4* __restrict__ boxes, float* __restrict__ bscores) {
  __shared__ unsigned long long keys[MCAP];
  __shared__ unsigned koff[SCAN_BLOCKS + 1];
  __shared__ unsigned mtot;
  const int n = blockIdx.y;
  const int tid = threadIdx.x;
  if (tid == 0) {
    unsigned acc = 0;
    for (int b = 0; b < SCAN_BLOCKS; ++b) { koff[b] = acc; acc += cnt[n * SCAN_BLOCKS + b]; }
    koff[SCAN_BLOCKS] = acc;
    unsigned sp = spill[n]; if (sp > SPILL) sp = SPILL;
    unsigned m = acc + sp; if (m > MCAP) m = MCAP;
    mtot = m;
  }
  __syncthreads();
  for (int s = tid; s < SCAN_BLOCKS * RSLOTS; s += 128) {
    int r = s / RSLOTS, k = s % RSLOTS;
    unsigned c = koff[r + 1] - koff[r];
    if ((unsigned)k < c) {
      unsigned d = koff[r] + (unsigned)k;
      if (d < MCAP) {
        unsigned vb = __float_as_uint(cval[n * CSLOTS + s]);
        keys[d] = ((unsigned long long)vb << 32) | (unsigned long long)(~cidx[n * CSLOTS + s]);
      }
    }
  }
  {
    unsigned sp = spill[n]; if (sp > SPILL) sp = SPILL;
    for (unsigned k = tid; k < sp; k += 128) {
      unsigned d = koff[SCAN_BLOCKS] + k;
      if (d < MCAP) {
        unsigned vb = __float_as_uint(cval[n * CSLOTS + SCAN_BLOCKS * RSLOTS + k]);
        keys[d] = ((unsigned long long)vb << 32) |
                  (unsigned long long)(~cidx[n * CSLOTS + SCAN_BLOCKS * RSLOTS + k]);
      }
    }
  }
  __syncthreads();
  const unsigned M = mtot;
  const unsigned c = blockIdx.x * 128 + (unsigned)tid;
  if (c >= M) return;
  const unsigned long long mykey = keys[c];
  unsigned rank = 0;
  for (unsigned t = 0; t < M; ++t) rank += (keys[t] > mykey) ? 1u : 0u;
  if (rank >= TOPK) return;
  const unsigned gi = ~(unsigned)(mykey & 0xFFFFFFFFull);
  const float val = __uint_as_float((unsigned)(mykey >> 32));
  const float wmax = (float)(isz[n * 2 + 1] - 1);
  const float hmax = (float)(isz[n * 2 + 0] - 1);
  const float* rg = reg + (size_t)n * 4 * HW;
  int wx = (int)gi % WW, hy = (int)gi / WW;
  float lx = (float)(wx * 8 + 4), ly = (float)(hy * 8 + 4);
  float l = rg[0 * HW + gi], tt = rg[1 * HW + gi];
  float rr = rg[2 * HW + gi], bb = rg[3 * HW + gi];
  float x1 = lx - l, y1 = ly - tt, x2 = lx + rr, y2 = ly + bb;
  x1 = fminf(fmaxf(x1, 0.0f), wmax);
  x2 = fminf(fmaxf(x2, 0.0f), wmax);
  y1 = fminf(fmaxf(y1, 0.0f), hmax);
  y2 = fminf(fmaxf(y2, 0.0f), hmax);
  float scr = val;
  if (!(((x2 - x1 + 1.0f) >= 0.0f) && ((y2 - y1 + 1.0f) >= 0.0f))) scr = NEGV;
  boxes[n * TOPK + rank] = make_float4(x1, y1, x2, y2);
  bscores[n * TOPK + rank] = scr;
}

// Pair-parallel IoU: stage all TOPK boxes in LDS (validity encoded as area sign),
// grid-stride the 1e6 rectangular pairs, emit i<j conflicts (rare) to edge list.
__global__ __launch_bounds__(256) void k_edges(
    const float4* __restrict__ boxes, const float* __restrict__ bscores,
    unsigned* __restrict__ ecnt, unsigned* __restrict__ edges) {
  __shared__ float4 sb[TOPK];
  __shared__ float saz[TOPK];  // valid ? area : -1
  const int n = blockIdx.y;
  const int tid = threadIdx.x;
  for (int k = tid; k < TOPK; k += 256) {
    float4 b = boxes[n * TOPK + k];
    sb[k] = b;
    float sc = bscores[n * TOPK + k];
    saz[k] = (sc > NEGV * 0.5f) ? (b.z - b.x) * (b.w - b.y) : -1.0f;
  }
  __syncthreads();
  for (unsigned q = blockIdx.x * 256u + (unsigned)tid; q < (unsigned)(TOPK * TOPK);
       q += EBLK * 256u) {
    unsigned i = q / TOPK, j = q % TOPK;  // consecutive lanes: same i, consecutive j
    if (i >= j) continue;
    float ai = saz[i], aj = saz[j];
    if (ai < 0.0f || aj < 0.0f) continue;
    float4 bi = sb[i], bj = sb[j];
    float ltx = fmaxf(bi.x, bj.x), lty = fmaxf(bi.y, bj.y);
    float rbx = fminf(bi.z, bj.z), rby = fminf(bi.w, bj.w);
    float wv = fmaxf(rbx - ltx, 0.0f), hv = fmaxf(rby - lty, 0.0f);
    float inter = wv * hv;
    float iou = inter / (ai + aj - inter + 1e-9f);
    if (iou > 0.6f) {
      unsigned pos = atomicAdd(&ecnt[n], 1u);  // rare (~tens/image)
      if (pos < ECAP) edges[n * ECAP + pos] = (i << 10) | j;
    }
  }
}

__global__ void k_final(const float* __restrict__ boxes, const float* __restrict__ bscores,
                        const unsigned* __restrict__ ecnt, const unsigned* __restrict__ edges,
                        float* __restrict__ out) {
  __shared__ unsigned eds[ECAP];
  __shared__ float ssc[TOPK];
  __shared__ unsigned char kept[TOPK];
  __shared__ int sel[100];
  __shared__ unsigned pfx[128];
  const int n = blockIdx.x;
  const int tid = threadIdx.x;
  unsigned E = ecnt[n]; if (E > ECAP) E = ECAP;
  for (int e = tid; e < TOPK; e += 128) { kept[e] = 1; ssc[e] = bscores[n * TOPK + e]; }
  for (int e = tid; e < (int)E; e += 128) eds[e] = edges[n * ECAP + e];
  if (tid < 100) sel[tid] = -1;
  __syncthreads();
  if (tid == 0) {
    for (int a = 1; a < (int)E; ++a) {
      unsigned v = eds[a]; int b = a - 1;
      while (b >= 0 && eds[b] > v) { eds[b + 1] = eds[b]; --b; }
      eds[b + 1] = v;
    }
    for (int e = 0; e < (int)E; ++e) {
      unsigned i = eds[e] >> 10, j = eds[e] & 1023u;
      if (kept[i]) kept[j] = 0;
    }
  }
  __syncthreads();
  int c = tid;
  unsigned cntk = 0;
  for (int k = 0; k < 8; ++k) {
    int e = c * 8 + k;
    if (e < TOPK && kept[e] && ssc[e] > NEGV * 0.5f) cntk++;
  }
  pfx[c] = cntk;
  __syncthreads();
  if (tid == 0) {
    unsigned acc = 0;
    for (int q = 0; q < 128; ++q) { unsigned t = pfx[q]; pfx[q] = acc; acc += t; }
  }
  __syncthreads();
  unsigned r = pfx[c];
  for (int k = 0; k < 8; ++k) {
    int e = c * 8 + k;
    if (e < TOPK && kept[e] && ssc[e] > NEGV * 0.5f) {
      if (r < 100) sel[r] = e;
      r++;
    }
  }
  __syncthreads();
  for (int k = tid; k < 100; k += 128) {
    int s = sel[k];
    float x1 = 0.f, y1 = 0.f, x2 = 0.f, y2 = 0.f, sc = 0.f, lab = 0.f, fv = 0.f;
    if (s >= 0) {
      float4 b = ((const float4*)boxes)[n * TOPK + s];
      x1 = b.x; y1 = b.y; x2 = b.z; y2 = b.w;
      sc = ssc[s]; lab = 1.0f; fv = 1.0f;
    }
    int o = (n * 100 + k) * 5;
    out[o + 0] = x1; out[o + 1] = y1; out[o + 2] = x2; out[o + 3] = y2; out[o + 4] = sc;
    out[NIMG * 500 + n * 100 + k] = lab;
    out[NIMG * 600 + n * 100 + k] = fv;
  }
}

extern "C" void kernel_launch(void* const* d_in, const int* in_sizes, int n_in,
                              void* d_out, int out_size, void* d_ws, size_t ws_size,
                              hipStream_t stream) {
  const float4* cls4 = (const float4*)d_in[1];
  const float* reg = (const float*)d_in[2];
  const float4* ctr4 = (const float4*)d_in[3];
  const int* isz = (const int*)d_in[4];
  float* out = (float*)d_out;
  uint8_t* w = (uint8_t*)d_ws;

  const size_t slicesA = (size_t)NIMG * SCAN_BLOCKS * NBINS * 4;  // 15,728,640
  const size_t histB = (size_t)NIMG * NBINS * 4;                  // 262,144
  const size_t tail = (size_t)NIMG * CSLOTS * 4 * 2
                    + (size_t)NIMG * SCAN_BLOCKS * 4
                    + (size_t)NIMG * TOPK * 4 * 4
                    + (size_t)NIMG * TOPK * 4
                    + (size_t)NIMG * ECAP * 4
                    + 64 + 64 + 64;
  const bool tierA = ws_size >= slicesA + tail;  // constant per session -> graph-safe

  unsigned* hist = (unsigned*)w;
  uint8_t* p = w + (tierA ? slicesA : histB);
  float* cval = (float*)p;       p += (size_t)NIMG * CSLOTS * 4;
  unsigned* cidx = (unsigned*)p; p += (size_t)NIMG * CSLOTS * 4;
  unsigned* cnt = (unsigned*)p;  p += (size_t)NIMG * SCAN_BLOCKS * 4;
  float* boxes = (float*)p;      p += (size_t)NIMG * TOPK * 4 * 4;
  float* bscores = (float*)p;    p += (size_t)NIMG * TOPK * 4;
  unsigned* edges = (unsigned*)p; p += (size_t)NIMG * ECAP * 4;
  unsigned* spill = (unsigned*)p; p += 64;
  unsigned* ecnt = (unsigned*)p;  p += 64;
  unsigned* bstar = (unsigned*)p;

  hipMemsetAsync(spill, 0, 128, stream);  // spill[16] + ecnt[16] (adjacent)
  if (!tierA) hipMemsetAsync(hist, 0, histB, stream);

  dim3 g1(SCAN_BLOCKS, NIMG);
  if (tierA) {
    k_scan<true><<<g1, SCAN_THREADS, 0, stream>>>(cls4, ctr4, hist);
    k_findbin<true><<<NIMG, 1024, 0, stream>>>(hist, bstar, (float4*)boxes, bscores);
  } else {
    k_scan<false><<<g1, SCAN_THREADS, 0, stream>>>(cls4, ctr4, hist);
    k_findbin<false><<<NIMG, 1024, 0, stream>>>(hist, bstar, (float4*)boxes, bscores);
  }
  k_collect2<<<g1, SCAN_THREADS, 0, stream>>>(cls4, ctr4, bstar, cval, cidx, cnt, spill);
  dim3 gr(RANK_BLOCKS, NIMG);
  k_rank<<<gr, 128, 0, stream>>>(cnt, spill, cval, cidx, reg, isz, (float4*)boxes, bscores);
  dim3 ge(EBLK, NIMG);
  k_edges<<<ge, 256, 0, stream>>>((const float4*)boxes, bscores, ecnt, edges);
  k_final<<<NIMG, 128, 0, stream>>>(boxes, bscores, ecnt, edges, out);
}

// Round 6
// 93.563 us; speedup vs baseline: 3.6076x; 1.1603x over previous
//
#include <hip/hip_runtime.h>
#include <cstdint>

// FCOS post-processor, MI355X — round 6.
// R5 postmortem: 512-bin coarsening grew candidate count M to ~1035, but k_rank
// had only 1024 ranking threads and NO grid-stride -> candidates >=1024 never
// ranked -> missing boxes. Fix: RANK_BLOCKS 8->16 (2048 = MCAP) + grid-stride
// loop so any M <= MCAP is fully covered. (R4 passed only by luck: M <= 1024.)
//
//  k_scan      : sm = cand ? sig(cls)*sig(ctr) : NEG ; per-block 512-bin LDS hist
//                -> private global slice [n][60][512] (no device atomics)
//  k_findbin   : reduce slices -> suffix-scan -> b* ; zero spill/ecnt;
//                prefill boxes=0 / bscores=NEG
//  k_collect2  : recompute sm, keep bin>=b*, LDS-compact -> partition [n][blk][72]+cnt
//  k_rank      : gather partitions, pack u64 keys (fbits(val)<<32|~idx),
//                rank = count(keys > mine) -> decode+clip -> boxes[rank]
//  k_edges     : stage 1000 boxes in LDS; pair-parallel IoU>0.6 -> edge list
//  k_final     : sort edges, exact greedy NMS, prefix-select first 100 kept, write out

#define NIMG 16
#define HH 400
#define WW 608
#define HW 243200
#define NF4 60800         // HW/4
#define TOPK 1000
#define NBINS 512
#define SCAN_BLOCKS 60    // per image
#define SCAN_THREADS 256
#define F4_PER_BLOCK 1024 // 60*1024*4 = 245760 >= 243200
#define RSLOTS 72         // partition slots per scan block (~17 expected, >12 sigma)
#define SPILL 32
#define CSLOTS (SCAN_BLOCKS * RSLOTS + SPILL)  // 4352 per image
#define MCAP 2048
#define RANK_BLOCKS 16    // per image, 128 threads each = 2048 = MCAP coverage
#define EBLK 32           // edge blocks per image
#define ECAP 8192
#define NEGV (-1e9f)

__device__ __forceinline__ float sigm(float x) { return 1.0f / (1.0f + expf(-x)); }

__device__ __forceinline__ int binof(float v) {
  if (!(v > 0.0f)) return 0;
  int b = (int)(v * (float)NBINS);
  return b > (NBINS - 1) ? (NBINS - 1) : b;
}

template <bool SLICES>
__global__ __launch_bounds__(SCAN_THREADS) void k_scan(
    const float4* __restrict__ cls, const float4* __restrict__ ctr,
    unsigned* __restrict__ hist) {
  __shared__ unsigned lh[NBINS];
  const int tid = threadIdx.x;
  for (int b = tid; b < NBINS; b += SCAN_THREADS) lh[b] = 0u;
  __syncthreads();
  const int n = blockIdx.y;
  const float4* c4 = cls + (size_t)n * NF4;
  const float4* t4 = ctr + (size_t)n * NF4;
  int base = blockIdx.x * F4_PER_BLOCK;
  float4 cv[4], tv[4];
  bool ok[4];
#pragma unroll
  for (int e = 0; e < 4; ++e) {
    int i = base + e * SCAN_THREADS + tid;
    ok[e] = (i < NF4);
    if (ok[e]) { cv[e] = c4[i]; tv[e] = t4[i]; }
  }
#pragma unroll
  for (int e = 0; e < 4; ++e) {
    if (ok[e]) {
      const float* cc = (const float*)&cv[e];
      const float* tt = (const float*)&tv[e];
#pragma unroll
      for (int k = 0; k < 4; ++k) {
        float sc = sigm(cc[k]);
        float sm = (sc > 0.05f) ? sc * sigm(tt[k]) : NEGV;
        atomicAdd(&lh[binof(sm)], 1u);  // LDS atomic: CU-local
      }
    }
  }
  __syncthreads();
  if (SLICES) {
    unsigned* gh = hist + ((size_t)n * SCAN_BLOCKS + blockIdx.x) * NBINS;
    for (int b = tid; b < NBINS; b += SCAN_THREADS) gh[b] = lh[b];
  } else {
    unsigned* gh = hist + (size_t)n * NBINS;
    for (int b = tid; b < NBINS; b += SCAN_THREADS) {
      unsigned v = lh[b];
      if (v) atomicAdd(&gh[b], v);
    }
  }
}

template <bool SLICES>
__global__ __launch_bounds__(128) void k_findbin(
    const unsigned* __restrict__ hist, unsigned* __restrict__ bstar,
    float4* __restrict__ boxes, float* __restrict__ bscores,
    unsigned* __restrict__ spill, unsigned* __restrict__ ecnt) {
  __shared__ unsigned h[NBINS];
  __shared__ unsigned chunk[32];
  const int n = blockIdx.x;
  const int tid = threadIdx.x;
  if (SLICES) {
    // 128 threads x (NBINS/4=128 uint4 groups): thread t sums group t over 60 slices
    uint4 s = make_uint4(0u, 0u, 0u, 0u);
    const uint4* base = (const uint4*)(hist + (size_t)n * SCAN_BLOCKS * NBINS);
    for (int b = 0; b < SCAN_BLOCKS; ++b) {
      uint4 v = base[b * (NBINS / 4) + tid];
      s.x += v.x; s.y += v.y; s.z += v.z; s.w += v.w;
    }
    ((uint4*)h)[tid] = s;
  } else {
    const unsigned* gh = hist + (size_t)n * NBINS;
    for (int b = tid; b < NBINS; b += 128) h[b] = gh[b];
  }
  // zero per-image counters (runs before k_collect2 / k_edges in stream order)
  if (tid == 0) { spill[n] = 0u; ecnt[n] = 0u; }
  // prefill output background (k_rank overwrites ranks < M)
  for (int k = tid; k < TOPK; k += 128) {
    boxes[n * TOPK + k] = make_float4(0.f, 0.f, 0.f, 0.f);
    bscores[n * TOPK + k] = NEGV;
  }
  __syncthreads();
  if (tid < 32) {
    unsigned s = 0;
    for (int k = 0; k < 16; ++k) s += h[tid * 16 + k];
    chunk[tid] = s;
  }
  __syncthreads();
  if (tid == 0) {
    unsigned cum = 0; int bs = 0; int cc;
    for (cc = 31; cc >= 0; --cc) {
      if (cum + chunk[cc] >= TOPK) break;
      cum += chunk[cc];
    }
    if (cc >= 0) {
      int b = cc * 16 + 15;
      for (;;) { cum += h[b]; if (cum >= TOPK || b == cc * 16) break; --b; }
      bs = b;
    }
    bstar[n] = (unsigned)bs;
  }
}

__global__ __launch_bounds__(SCAN_THREADS) void k_collect2(
    const float4* __restrict__ cls, const float4* __restrict__ ctr,
    const unsigned* __restrict__ bstar,
    float* __restrict__ cval, unsigned* __restrict__ cidx,
    unsigned* __restrict__ cnt, unsigned* __restrict__ spill) {
  __shared__ float sval[RSLOTS];
  __shared__ unsigned sidx[RSLOTS];
  __shared__ unsigned scnt;
  const int n = blockIdx.y;
  const int tid = threadIdx.x;
  if (tid == 0) scnt = 0u;
  __syncthreads();
  const unsigned bs = bstar[n];
  const float4* c4 = cls + (size_t)n * NF4;
  const float4* t4 = ctr + (size_t)n * NF4;
  int base = blockIdx.x * F4_PER_BLOCK;
  float4 cv[4], tv[4];
  bool ok[4];
#pragma unroll
  for (int e = 0; e < 4; ++e) {
    int i = base + e * SCAN_THREADS + tid;
    ok[e] = (i < NF4);
    if (ok[e]) { cv[e] = c4[i]; tv[e] = t4[i]; }
  }
#pragma unroll
  for (int e = 0; e < 4; ++e) {
    if (ok[e]) {
      const float* cc = (const float*)&cv[e];
      const float* tt = (const float*)&tv[e];
#pragma unroll
      for (int k = 0; k < 4; ++k) {
        float sc = sigm(cc[k]);
        float sm = (sc > 0.05f) ? sc * sigm(tt[k]) : NEGV;
        if (sm > NEGV * 0.5f && (unsigned)binof(sm) >= bs) {
          unsigned gi = (unsigned)((base + e * SCAN_THREADS + tid) * 4 + k);
          unsigned p = atomicAdd(&scnt, 1u);  // LDS atomic
          if (p < RSLOTS) {
            sval[p] = sm; sidx[p] = gi;
          } else {
            unsigned q = atomicAdd(&spill[n], 1u);  // rare overflow only
            if (q < SPILL) {
              cval[n * CSLOTS + SCAN_BLOCKS * RSLOTS + q] = sm;
              cidx[n * CSLOTS + SCAN_BLOCKS * RSLOTS + q] = gi;
            }
          }
        }
      }
    }
  }
  __syncthreads();
  unsigned m = scnt; if (m > RSLOTS) m = RSLOTS;
  if (tid < m) {
    cval[n * CSLOTS + blockIdx.x * RSLOTS + tid] = sval[tid];
    cidx[n * CSLOTS + blockIdx.x * RSLOTS + tid] = sidx[tid];
  }
  if (tid == 0) cnt[n * SCAN_BLOCKS + blockIdx.x] = m;
}

// Rank-by-counting: key = (fbits(val)<<32)|~idx is monotone for (val desc, idx asc)
// == jax.lax.top_k order. rank = #{keys > mine}; ranks distinct -> direct scatter.
// Grid-stride over candidates: RANK_BLOCKS*128 = MCAP threads cover any M <= MCAP.
__global__ __launch_bounds__(128) void k_rank(
    const unsigned* __restrict__ cnt, const unsigned* __restrict__ spill,
    const float* __restrict__ cval, const unsigned* __restrict__ cidx,
    const float* __restrict__ reg, const int* __restrict__ isz,
    float4* __restrict__ boxes, float* __restrict__ bscores) {
  __shared__ unsigned long long keys[MCAP];
  __shared__ unsigned koff[SCAN_BLOCKS + 1];
  __shared__ unsigned mtot;
  const int n = blockIdx.y;
  const int tid = threadIdx.x;
  if (tid == 0) {
    unsigned acc = 0;
    for (int b = 0; b < SCAN_BLOCKS; ++b) { koff[b] = acc; acc += cnt[n * SCAN_BLOCKS + b]; }
    koff[SCAN_BLOCKS] = acc;
    unsigned sp = spill[n]; if (sp > SPILL) sp = SPILL;
    unsigned m = acc + sp; if (m > MCAP) m = MCAP;
    mtot = m;
  }
  __syncthreads();
  for (int s = tid; s < SCAN_BLOCKS * RSLOTS; s += 128) {
    int r = s / RSLOTS, k = s % RSLOTS;
    unsigned c = koff[r + 1] - koff[r];
    if ((unsigned)k < c) {
      unsigned d = koff[r] + (unsigned)k;
      if (d < MCAP) {
        unsigned vb = __float_as_uint(cval[n * CSLOTS + s]);
        keys[d] = ((unsigned long long)vb << 32) | (unsigned long long)(~cidx[n * CSLOTS + s]);
      }
    }
  }
  {
    unsigned sp = spill[n]; if (sp > SPILL) sp = SPILL;
    for (unsigned k = tid; k < sp; k += 128) {
      unsigned d = koff[SCAN_BLOCKS] + k;
      if (d < MCAP) {
        unsigned vb = __float_as_uint(cval[n * CSLOTS + SCAN_BLOCKS * RSLOTS + k]);
        keys[d] = ((unsigned long long)vb << 32) |
                  (unsigned long long)(~cidx[n * CSLOTS + SCAN_BLOCKS * RSLOTS + k]);
      }
    }
  }
  __syncthreads();
  const unsigned M = mtot;
  const float wmax = (float)(isz[n * 2 + 1] - 1);
  const float hmax = (float)(isz[n * 2 + 0] - 1);
  const float* rg = reg + (size_t)n * 4 * HW;
  for (unsigned c = blockIdx.x * 128u + (unsigned)tid; c < M; c += RANK_BLOCKS * 128u) {
    const unsigned long long mykey = keys[c];
    unsigned rank = 0;
    for (unsigned t = 0; t < M; ++t) rank += (keys[t] > mykey) ? 1u : 0u;
    if (rank >= TOPK) continue;
    const unsigned gi = ~(unsigned)(mykey & 0xFFFFFFFFull);
    const float val = __uint_as_float((unsigned)(mykey >> 32));
    int wx = (int)gi % WW, hy = (int)gi / WW;
    float lx = (float)(wx * 8 + 4), ly = (float)(hy * 8 + 4);
    float l = rg[0 * HW + gi], tt = rg[1 * HW + gi];
    float rr = rg[2 * HW + gi], bb = rg[3 * HW + gi];
    float x1 = lx - l, y1 = ly - tt, x2 = lx + rr, y2 = ly + bb;
    x1 = fminf(fmaxf(x1, 0.0f), wmax);
    x2 = fminf(fmaxf(x2, 0.0f), wmax);
    y1 = fminf(fmaxf(y1, 0.0f), hmax);
    y2 = fminf(fmaxf(y2, 0.0f), hmax);
    float scr = val;
    if (!(((x2 - x1 + 1.0f) >= 0.0f) && ((y2 - y1 + 1.0f) >= 0.0f))) scr = NEGV;
    boxes[n * TOPK + rank] = make_float4(x1, y1, x2, y2);
    bscores[n * TOPK + rank] = scr;
  }
}

// Pair-parallel IoU: stage all TOPK boxes in LDS (validity encoded as area sign),
// grid-stride the 1e6 rectangular pairs, emit i<j conflicts (rare) to edge list.
__global__ __launch_bounds__(256) void k_edges(
    const float4* __restrict__ boxes, const float* __restrict__ bscores,
    unsigned* __restrict__ ecnt, unsigned* __restrict__ edges) {
  __shared__ float4 sb[TOPK];
  __shared__ float saz[TOPK];  // valid ? area : -1
  const int n = blockIdx.y;
  const int tid = threadIdx.x;
  for (int k = tid; k < TOPK; k += 256) {
    float4 b = boxes[n * TOPK + k];
    sb[k] = b;
    float sc = bscores[n * TOPK + k];
    saz[k] = (sc > NEGV * 0.5f) ? (b.z - b.x) * (b.w - b.y) : -1.0f;
  }
  __syncthreads();
  for (unsigned q = blockIdx.x * 256u + (unsigned)tid; q < (unsigned)(TOPK * TOPK);
       q += EBLK * 256u) {
    unsigned i = q / TOPK, j = q % TOPK;  // consecutive lanes: same i, consecutive j
    if (i >= j) continue;
    float ai = saz[i], aj = saz[j];
    if (ai < 0.0f || aj < 0.0f) continue;
    float4 bi = sb[i], bj = sb[j];
    float ltx = fmaxf(bi.x, bj.x), lty = fmaxf(bi.y, bj.y);
    float rbx = fminf(bi.z, bj.z), rby = fminf(bi.w, bj.w);
    float wv = fmaxf(rbx - ltx, 0.0f), hv = fmaxf(rby - lty, 0.0f);
    float inter = wv * hv;
    float iou = inter / (ai + aj - inter + 1e-9f);
    if (iou > 0.6f) {
      unsigned pos = atomicAdd(&ecnt[n], 1u);  // rare (~tens/image)
      if (pos < ECAP) edges[n * ECAP + pos] = (i << 10) | j;
    }
  }
}

__global__ void k_final(const float* __restrict__ boxes, const float* __restrict__ bscores,
                        const unsigned* __restrict__ ecnt, const unsigned* __restrict__ edges,
                        float* __restrict__ out) {
  __shared__ unsigned eds[ECAP];
  __shared__ float ssc[TOPK];
  __shared__ unsigned char kept[TOPK];
  __shared__ int sel[100];
  __shared__ unsigned pfx[128];
  const int n = blockIdx.x;
  const int tid = threadIdx.x;
  unsigned E = ecnt[n]; if (E > ECAP) E = ECAP;
  for (int e = tid; e < TOPK; e += 128) { kept[e] = 1; ssc[e] = bscores[n * TOPK + e]; }
  for (int e = tid; e < (int)E; e += 128) eds[e] = edges[n * ECAP + e];
  if (tid < 100) sel[tid] = -1;
  __syncthreads();
  if (tid == 0) {
    for (int a = 1; a < (int)E; ++a) {
      unsigned v = eds[a]; int b = a - 1;
      while (b >= 0 && eds[b] > v) { eds[b + 1] = eds[b]; --b; }
      eds[b + 1] = v;
    }
    for (int e = 0; e < (int)E; ++e) {
      unsigned i = eds[e] >> 10, j = eds[e] & 1023u;
      if (kept[i]) kept[j] = 0;
    }
  }
  __syncthreads();
  int c = tid;
  unsigned cntk = 0;
  for (int k = 0; k < 8; ++k) {
    int e = c * 8 + k;
    if (e < TOPK && kept[e] && ssc[e] > NEGV * 0.5f) cntk++;
  }
  pfx[c] = cntk;
  __syncthreads();
  if (tid == 0) {
    unsigned acc = 0;
    for (int q = 0; q < 128; ++q) { unsigned t = pfx[q]; pfx[q] = acc; acc += t; }
  }
  __syncthreads();
  unsigned r = pfx[c];
  for (int k = 0; k < 8; ++k) {
    int e = c * 8 + k;
    if (e < TOPK && kept[e] && ssc[e] > NEGV * 0.5f) {
      if (r < 100) sel[r] = e;
      r++;
    }
  }
  __syncthreads();
  for (int k = tid; k < 100; k += 128) {
    int s = sel[k];
    float x1 = 0.f, y1 = 0.f, x2 = 0.f, y2 = 0.f, sc = 0.f, lab = 0.f, fv = 0.f;
    if (s >= 0) {
      float4 b = ((const float4*)boxes)[n * TOPK + s];
      x1 = b.x; y1 = b.y; x2 = b.z; y2 = b.w;
      sc = ssc[s]; lab = 1.0f; fv = 1.0f;
    }
    int o = (n * 100 + k) * 5;
    out[o + 0] = x1; out[o + 1] = y1; out[o + 2] = x2; out[o + 3] = y2; out[o + 4] = sc;
    out[NIMG * 500 + n * 100 + k] = lab;
    out[NIMG * 600 + n * 100 + k] = fv;
  }
}

extern "C" void kernel_launch(void* const* d_in, const int* in_sizes, int n_in,
                              void* d_out, int out_size, void* d_ws, size_t ws_size,
                              hipStream_t stream) {
  const float4* cls4 = (const float4*)d_in[1];
  const float* reg = (const float*)d_in[2];
  const float4* ctr4 = (const float4*)d_in[3];
  const int* isz = (const int*)d_in[4];
  float* out = (float*)d_out;
  uint8_t* w = (uint8_t*)d_ws;

  const size_t slicesA = (size_t)NIMG * SCAN_BLOCKS * NBINS * 4;  // 1,966,080
  const size_t histB = (size_t)NIMG * NBINS * 4;                  // 32,768
  const size_t tail = (size_t)NIMG * CSLOTS * 4 * 2
                    + (size_t)NIMG * SCAN_BLOCKS * 4
                    + (size_t)NIMG * TOPK * 4 * 4
                    + (size_t)NIMG * TOPK * 4
                    + (size_t)NIMG * ECAP * 4
                    + 64 + 64 + 64;
  const bool tierA = ws_size >= slicesA + tail;  // constant per session -> graph-safe

  unsigned* hist = (unsigned*)w;
  uint8_t* p = w + (tierA ? slicesA : histB);
  float* cval = (float*)p;       p += (size_t)NIMG * CSLOTS * 4;
  unsigned* cidx = (unsigned*)p; p += (size_t)NIMG * CSLOTS * 4;
  unsigned* cnt = (unsigned*)p;  p += (size_t)NIMG * SCAN_BLOCKS * 4;
  float* boxes = (float*)p;      p += (size_t)NIMG * TOPK * 4 * 4;
  float* bscores = (float*)p;    p += (size_t)NIMG * TOPK * 4;
  unsigned* edges = (unsigned*)p; p += (size_t)NIMG * ECAP * 4;
  unsigned* spill = (unsigned*)p; p += 64;
  unsigned* ecnt = (unsigned*)p;  p += 64;
  unsigned* bstar = (unsigned*)p;

  if (!tierA) hipMemsetAsync(hist, 0, histB, stream);  // fallback tier only

  dim3 g1(SCAN_BLOCKS, NIMG);
  if (tierA) {
    k_scan<true><<<g1, SCAN_THREADS, 0, stream>>>(cls4, ctr4, hist);
    k_findbin<true><<<NIMG, 128, 0, stream>>>(hist, bstar, (float4*)boxes, bscores, spill, ecnt);
  } else {
    k_scan<false><<<g1, SCAN_THREADS, 0, stream>>>(cls4, ctr4, hist);
    k_findbin<false><<<NIMG, 128, 0, stream>>>(hist, bstar, (float4*)boxes, bscores, spill, ecnt);
  }
  k_collect2<<<g1, SCAN_THREADS, 0, stream>>>(cls4, ctr4, bstar, cval, cidx, cnt, spill);
  dim3 gr(RANK_BLOCKS, NIMG);
  k_rank<<<gr, 128, 0, stream>>>(cnt, spill, cval, cidx, reg, isz, (float4*)boxes, bscores);
  dim3 ge(EBLK, NIMG);
  k_edges<<<ge, 256, 0, stream>>>((const float4*)boxes, bscores, ecnt, edges);
  k_final<<<NIMG, 128, 0, stream>>>(boxes, bscores, ecnt, edges, out);
}